// Round 5
// baseline (66333.289 us; speedup 1.0000x reference)
//
#include <hip/hip_runtime.h>
#include <math.h>

#define HD 512
#define TT 512
#define NB 128
#define MAGIC 0x13579BDFu
typedef unsigned int uint;

__device__ __forceinline__ float sigm(float v) { return 1.0f / (1.0f + __expf(-v)); }

// Cross-WG data: relaxed agent-scope atomics -> per-access L1/L2 bypass (sc0 sc1),
// coherent at LLC, NO buffer_inv / buffer_wbl2 cache maintenance.
__device__ __forceinline__ float2 gld2(const float2* p) {
    unsigned long long v = __hip_atomic_load((const unsigned long long*)p,
                                             __ATOMIC_RELAXED, __HIP_MEMORY_SCOPE_AGENT);
    union { unsigned long long u; float2 f; } c; c.u = v; return c.f;
}
__device__ __forceinline__ void gst(float* p, float v) {
    __hip_atomic_store(p, v, __ATOMIC_RELAXED, __HIP_MEMORY_SCOPE_AGENT);
}

// x: [128][512] -> xT: [512][128]
__global__ __launch_bounds__(256) void transpose_x(const float* __restrict__ x,
                                                   float* __restrict__ xT) {
    __shared__ float tile[32][33];
    int bx = blockIdx.x * 32;
    int by = blockIdx.y * 32;
    int tx = threadIdx.x & 31, ty = threadIdx.x >> 5;
    #pragma unroll
    for (int i = 0; i < 32; i += 8)
        tile[ty + i][tx] = x[(by + ty + i) * TT + bx + tx];
    __syncthreads();
    #pragma unroll
    for (int i = 0; i < 32; i += 8)
        xT[(bx + ty + i) * NB + by + tx] = tile[tx][ty + i];
}

// Barrier over 64 WGs of one batch-group. Lines (x32 uints): 0,1 = sub-counters
// (32 WGs each), 2 = root, 3 = generation, 4 = init-ready magic.
// No fences: __syncthreads drains vmcnt(0) (h stores at coherent point before
// leader arrives); shared data is per-access bypassing, no invalidate needed.
__device__ __forceinline__ void gbar(uint* mybar, int subid, uint n) {
    __syncthreads();
    if (threadIdx.x == 0) {
        uint old = __hip_atomic_fetch_add(mybar + subid * 32, 1u,
                                          __ATOMIC_RELAXED, __HIP_MEMORY_SCOPE_AGENT);
        if (old == 32u * (n + 1u) - 1u) {
            uint r = __hip_atomic_fetch_add(mybar + 2 * 32, 1u,
                                            __ATOMIC_RELAXED, __HIP_MEMORY_SCOPE_AGENT);
            if (r == 2u * (n + 1u) - 1u)
                __hip_atomic_store(mybar + 3 * 32, n + 1u,
                                   __ATOMIC_RELAXED, __HIP_MEMORY_SCOPE_AGENT);
        }
        while (__hip_atomic_load(mybar + 3 * 32, __ATOMIC_RELAXED,
                                 __HIP_MEMORY_SCOPE_AGENT) < n + 1u)
            __builtin_amdgcn_s_sleep(1);
    }
    __syncthreads();
}

// h paired-float2 layout: float2 index ((phase*2+bg)*256 + k2)*64 + lane.
#define LOADC(BUF, C) { _Pragma("unroll") \
    for (int j = 0; j < 16; ++j) \
        BUF[j] = gld2(h2src + (size_t)(kb2 + (C) * 16 + j) * 64 + lane); }

// 8 units x 3 gates over one float2 of h. Weights: uniform scalar-path streams.
#define FMAE(BUF, C) { _Pragma("unroll") \
    for (int j = 0; j < 16; ++j) { \
        const int k0 = (kb2 + (C) * 16 + j) * 2; \
        const float ha = BUF[j].x, hb = BUF[j].y; \
        _Pragma("unroll") \
        for (int m = 0; m < 8; ++m) { \
            aR[m] = fmaf(wR[m * HD + k0 + 1], hb, fmaf(wR[m * HD + k0], ha, aR[m])); \
            aZ[m] = fmaf(wZ[m * HD + k0 + 1], hb, fmaf(wZ[m * HD + k0], ha, aZ[m])); \
            aN[m] = fmaf(wN[m * HD + k0 + 1], hb, fmaf(wN[m * HD + k0], ha, aN[m])); \
        } } }

#define FMAD(BUF, C) { _Pragma("unroll") \
    for (int j = 0; j < 16; ++j) { \
        const int k0 = (kb2 + (C) * 16 + j) * 2; \
        const float ha = BUF[j].x, hb = BUF[j].y; \
        _Pragma("unroll") \
        for (int m = 0; m < 8; ++m) { \
            aR[m] = fmaf(wR[m * HD + k0 + 1], hb, fmaf(wR[m * HD + k0], ha, aR[m])); \
            aZ[m] = fmaf(wZ[m * HD + k0 + 1], hb, fmaf(wZ[m * HD + k0], ha, aZ[m])); \
            aN[m] = fmaf(wN[m * HD + k0 + 1], hb, fmaf(wN[m * HD + k0], ha, aN[m])); \
        } \
        ay = fmaf(lw[k0 + 1], hb, fmaf(lw[k0], ha, ay)); } }

// 128 WGs = 2 batch-groups x 64 unit-groups; 512 threads = 8 waves (2/SIMD).
// WG owns 8 units; wave wv: k in [64*wv, 64*wv+64) for all 8, finalizes unit u0+wv.
__global__ __launch_bounds__(512, 1) void gru_ae(
    const float* __restrict__ xT,
    const float* __restrict__ eWi, const float* __restrict__ eWh,
    const float* __restrict__ ebi, const float* __restrict__ ebh,
    const float* __restrict__ dWi, const float* __restrict__ dWh,
    const float* __restrict__ dbi, const float* __restrict__ dbh,
    const float* __restrict__ linW, const float* __restrict__ linb,
    float* __restrict__ hbuf, uint* __restrict__ bar,
    float* __restrict__ out)
{
    const int bg    = blockIdx.x >> 6;
    const int wgu   = blockIdx.x & 63;
    const int lane  = threadIdx.x & 63;
    const int wv    = __builtin_amdgcn_readfirstlane(threadIdx.x >> 6); // 0..7
    const int kb2   = wv * 32;            // float2-pair base of this wave's k-range
    const int u0    = wgu * 8;
    const int u     = u0 + wv;            // unit this wave finalizes
    const int col   = bg * 64 + lane;     // batch column
    const int subid = wgu >> 5;
    uint* mybar = bar + bg * 8 * 32;

    __shared__ float part[8][25][64];

    // ---- init barrier counters (d_ws is poisoned each call) ----
    if (wgu == 0 && threadIdx.x == 0) {
        for (int i = 0; i < 4; ++i)
            __hip_atomic_store(mybar + i * 32, 0u, __ATOMIC_RELAXED, __HIP_MEMORY_SCOPE_AGENT);
        __builtin_amdgcn_s_waitcnt(0x0F70);   // vmcnt(0): zeros visible before MAGIC
        __hip_atomic_store(mybar + 4 * 32, MAGIC, __ATOMIC_RELAXED, __HIP_MEMORY_SCOPE_AGENT);
    }
    if (threadIdx.x == 0) {
        while (__hip_atomic_load(mybar + 4 * 32, __ATOMIC_RELAXED,
                                 __HIP_MEMORY_SCOPE_AGENT) != MAGIC)
            __builtin_amdgcn_s_sleep(1);
    }
    __syncthreads();

    // zero h phase 0: this wave's unit row (paired layout: (u>>1, lane, u&1))
    gst(&hbuf[(size_t)((0 * 2 + bg) * 256 + (u >> 1)) * 128 + lane * 2 + (u & 1)], 0.0f);

    uint bn = 0;
    gbar(mybar, subid, bn); ++bn;

    const float lb = linb[0];
    const float* lw = linW;
    float hprev = 0.0f;   // own unit's h, register-resident
    int p = 0;

    // ---------------- encoder ----------------
    {
        const float* wR = eWh + (size_t)(0 * HD + u0) * HD;
        const float* wZ = eWh + (size_t)(1 * HD + u0) * HD;
        const float* wN = eWh + (size_t)(2 * HD + u0) * HD;
        const float wi_r = eWi[u], wi_z = eWi[HD + u], wi_n = eWi[2 * HD + u];
        const float cr  = ebi[u] + ebh[u];
        const float cz  = ebi[HD + u] + ebh[HD + u];
        const float bin = ebi[2 * HD + u], bhn = ebh[2 * HD + u];

        for (int s = 0; s < TT; ++s) {
            const float2* h2src = (const float2*)hbuf + (size_t)(p * 2 + bg) * 256 * 64;
            float xt = xT[s * NB + col];
            float aR[8], aZ[8], aN[8];
            #pragma unroll
            for (int m = 0; m < 8; ++m) { aR[m] = 0.f; aZ[m] = 0.f; aN[m] = 0.f; }
            float2 bA[16], bB[16];
            LOADC(bA, 0)
            LOADC(bB, 1)
            FMAE(bA, 0)
            FMAE(bB, 1)

            #pragma unroll
            for (int m = 0; m < 8; ++m) {
                part[wv][m * 3 + 0][lane] = aR[m];
                part[wv][m * 3 + 1][lane] = aZ[m];
                part[wv][m * 3 + 2][lane] = aN[m];
            }
            __syncthreads();

            float ar = 0.f, az = 0.f, an = 0.f;
            #pragma unroll
            for (int w = 0; w < 8; ++w) {
                ar += part[w][wv * 3 + 0][lane];
                az += part[w][wv * 3 + 1][lane];
                an += part[w][wv * 3 + 2][lane];
            }

            float r = sigm(fmaf(xt, wi_r, cr) + ar);
            float z = sigm(fmaf(xt, wi_z, cz) + az);
            float n = tanhf(fmaf(xt, wi_n, bin) + r * (an + bhn));
            float hv = fmaf(z, hprev - n, n);
            gst(&hbuf[(size_t)(((p ^ 1) * 2 + bg) * 256 + (u >> 1)) * 128 + lane * 2 + (u & 1)], hv);
            hprev = hv;
            p ^= 1;
            gbar(mybar, subid, bn); ++bn;
        }
    }

    // ---------------- decoder ----------------
    {
        const float* wR = dWh + (size_t)(0 * HD + u0) * HD;
        const float* wZ = dWh + (size_t)(1 * HD + u0) * HD;
        const float* wN = dWh + (size_t)(2 * HD + u0) * HD;
        const float wi_r = dWi[u], wi_z = dWi[HD + u], wi_n = dWi[2 * HD + u];
        const float cr  = dbi[u] + dbh[u];
        const float cz  = dbi[HD + u] + dbh[HD + u];
        const float bin = dbi[2 * HD + u], bhn = dbh[2 * HD + u];

        for (int s = 0; s < TT; ++s) {
            const float2* h2src = (const float2*)hbuf + (size_t)(p * 2 + bg) * 256 * 64;
            float aR[8], aZ[8], aN[8];
            #pragma unroll
            for (int m = 0; m < 8; ++m) { aR[m] = 0.f; aZ[m] = 0.f; aN[m] = 0.f; }
            float ay = 0.0f;
            float2 bA[16], bB[16];
            LOADC(bA, 0)
            LOADC(bB, 1)
            FMAD(bA, 0)
            FMAD(bB, 1)

            #pragma unroll
            for (int m = 0; m < 8; ++m) {
                part[wv][m * 3 + 0][lane] = aR[m];
                part[wv][m * 3 + 1][lane] = aZ[m];
                part[wv][m * 3 + 2][lane] = aN[m];
            }
            part[wv][24][lane] = ay;
            __syncthreads();

            float ar = 0.f, az = 0.f, an = 0.f, y = lb;
            #pragma unroll
            for (int w = 0; w < 8; ++w) {
                ar += part[w][wv * 3 + 0][lane];
                az += part[w][wv * 3 + 1][lane];
                an += part[w][wv * 3 + 2][lane];
                y  += part[w][24][lane];
            }

            if (wgu == 0 && wv == 0 && s > 0)
                out[col * TT + (TT - s)] = y;   // y_{s-1} -> column TT-1-(s-1)

            float r = sigm(fmaf(y, wi_r, cr) + ar);
            float z = sigm(fmaf(y, wi_z, cz) + az);
            float n = tanhf(fmaf(y, wi_n, bin) + r * (an + bhn));
            float hv = fmaf(z, hprev - n, n);
            gst(&hbuf[(size_t)(((p ^ 1) * 2 + bg) * 256 + (u >> 1)) * 128 + lane * 2 + (u & 1)], hv);
            hprev = hv;
            p ^= 1;
            gbar(mybar, subid, bn); ++bn;
        }
    }

    // final y_511 = lin(h_511) -> out[:, 0]
    if (wgu == 0) {
        const float2* h2src = (const float2*)hbuf + (size_t)(p * 2 + bg) * 256 * 64;
        float ay = 0.0f;
        #pragma unroll 8
        for (int j = 0; j < 32; ++j) {
            float2 hh = gld2(h2src + (size_t)(kb2 + j) * 64 + lane);
            const int k0 = (kb2 + j) * 2;
            ay = fmaf(lw[k0 + 1], hh.y, fmaf(lw[k0], hh.x, ay));
        }
        part[wv][0][lane] = ay;
        __syncthreads();
        if (wv == 0) {
            float y = lb;
            #pragma unroll
            for (int w = 0; w < 8; ++w) y += part[w][0][lane];
            out[col * TT + 0] = y;
        }
    }
}

extern "C" void kernel_launch(void* const* d_in, const int* in_sizes, int n_in,
                              void* d_out, int out_size, void* d_ws, size_t ws_size,
                              hipStream_t stream) {
    const float* x    = (const float*)d_in[0];
    const float* eWi  = (const float*)d_in[1];
    const float* eWh  = (const float*)d_in[2];
    const float* ebi  = (const float*)d_in[3];
    const float* ebh  = (const float*)d_in[4];
    const float* dWi  = (const float*)d_in[5];
    const float* dWh  = (const float*)d_in[6];
    const float* dbi  = (const float*)d_in[7];
    const float* dbh  = (const float*)d_in[8];
    const float* linW = (const float*)d_in[9];
    const float* linb = (const float*)d_in[10];
    float* out = (float*)d_out;

    float* hbuf = (float*)d_ws;                                   // 2*2*256*128 floats = 512 KB
    float* xT   = hbuf + 2 * 2 * 256 * 128;                       // 256 KB
    uint*  bar  = (uint*)(xT + HD * NB);                          // 2 KB

    transpose_x<<<dim3(16, 4), dim3(256), 0, stream>>>(x, xT);
    gru_ae<<<dim3(128), dim3(512), 0, stream>>>(xT, eWi, eWh, ebi, ebh,
                                                dWi, dWh, dbi, dbh,
                                                linW, linb, hbuf, bar, out);
}